// Round 1
// baseline (6293.810 us; speedup 1.0000x reference)
//
#include <hip/hip_runtime.h>
#include <math.h>
#include <stddef.h>

// ---------------------------------------------------------------------------
// ReNet-style: patches -> vertical bidir LSTM -> horizontal bidir LSTM -> dense
// B=64, I=J=32, D=12, HID=256, FC=1024.
// Round 1: correctness-first fp32, fused gate epilogue in the step GEMM.
// ---------------------------------------------------------------------------

namespace {

constexpr int HID = 256;
constexpr int NROW = 2048;                       // B*J == B*I
constexpr size_t VSZ  = (size_t)64 * 32 * 32 * 512;   // 33554432 floats
constexpr size_t HPSZ = (size_t)2 * 2 * NROW * HID;   // ping x dir x rows x hid
constexpr size_t CSZ  = (size_t)2 * NROW * HID;

__device__ __forceinline__ float sigm(float x) { return 1.0f / (1.0f + __expf(-x)); }

// Inner product accumulation: tile is 32 rows x 256 cols (4 gates x 64 h).
// Thread (tx,ty): rows ty*2, ty*2+1 ; cols per gate g: g*64 + tx*4 .. +3.
#define LSTM_INNER(KK)                                                    \
  {                                                                       \
    _Pragma("unroll")                                                     \
    for (int kk = 0; kk < (KK); ++kk) {                                   \
      const float a0 = As[kk][(ty << 1) + 0];                             \
      const float a1 = As[kk][(ty << 1) + 1];                             \
      _Pragma("unroll")                                                   \
      for (int g = 0; g < 4; ++g) {                                       \
        const float4 bq = *(const float4*)&Bs[kk][(g << 6) + (tx << 2)];  \
        acc0[(g << 2) + 0] += a0 * bq.x;  acc1[(g << 2) + 0] += a1 * bq.x;\
        acc0[(g << 2) + 1] += a0 * bq.y;  acc1[(g << 2) + 1] += a1 * bq.y;\
        acc0[(g << 2) + 2] += a0 * bq.z;  acc1[(g << 2) + 2] += a1 * bq.z;\
        acc0[(g << 2) + 3] += a0 * bq.w;  acc1[(g << 2) + 3] += a1 * bq.w;\
      }                                                                   \
    }                                                                     \
  }

// One LSTM time step, both directions (blockIdx.z), fused gates.
// VERT: A_x gathered from x patches (K=12), h written to v[b][i][j][dir*256+h]
// !VERT: A_x read from v rows (K=512),  h written to hfinal[b][i][j][dir*256+h]
template <bool VERT>
__global__ __launch_bounds__(256) void lstm_step(
    const float* __restrict__ xin,  // x (VERT) or v (!VERT)
    const float* __restrict__ kf, const float* __restrict__ rf, const float* __restrict__ bf,
    const float* __restrict__ kb, const float* __restrict__ rb, const float* __restrict__ bb,
    const float* __restrict__ hprev, float* __restrict__ hnext,
    float* __restrict__ cst, float* __restrict__ hout, int t) {
  const int tid = threadIdx.x;
  const int tx = tid & 15;
  const int ty = tid >> 4;
  const int h0 = blockIdx.x << 6;       // 0..3 -> h block of 64
  const int rowBase = blockIdx.y << 5;  // 0..63 -> 32 rows
  const int dir = blockIdx.z;
  const int seq = dir ? (31 - t) : t;
  const float* kw = dir ? kb : kf;
  const float* rw = dir ? rb : rf;
  const float* bw = dir ? bb : bf;

  __shared__ float As[16][33];
  __shared__ float Bs[16][256];

  float acc0[16];
  float acc1[16];
#pragma unroll
  for (int q = 0; q < 16; ++q) { acc0[q] = 0.f; acc1[q] = 0.f; }

  // B-tile load column: tile col c = tid ; gate = c>>6 ; hh = c&63
  const int gcol = ((tid >> 6) << 8) + h0 + (tid & 63);

  if (VERT) {
    // ---- input projection, K = 12 (patch dims) ----
    for (int e = tid; e < 32 * 12; e += 256) {
      const int m = e / 12, kk = e - m * 12;
      const int n = rowBase + m;
      const int b = n >> 5, j = n & 31;
      const int pr = kk / 6, rem = kk - pr * 6;  // rem = pc*3 + c (6 contiguous)
      As[kk][m] = xin[((size_t)(b * 64 + (seq << 1) + pr) * 64 + (j << 1)) * 3 + rem];
    }
#pragma unroll
    for (int rep = 0; rep < 12; ++rep) Bs[rep][tid] = kw[rep * 1024 + gcol];
    __syncthreads();
    LSTM_INNER(12)
    __syncthreads();
  } else {
    // ---- input projection, K = 512 (v rows) ----
    for (int k0 = 0; k0 < 512; k0 += 16) {
      const int n1 = rowBase + ty;
      As[tx][ty]      = xin[((size_t)n1 * 32 + seq) * 512 + k0 + tx];
      As[tx][ty + 16] = xin[((size_t)(n1 + 16) * 32 + seq) * 512 + k0 + tx];
#pragma unroll
      for (int rep = 0; rep < 16; ++rep)
        Bs[rep][tid] = kw[(size_t)(k0 + rep) * 1024 + gcol];
      __syncthreads();
      LSTM_INNER(16)
      __syncthreads();
    }
  }

  // ---- recurrent projection, K = 256 ----
  const float* hp = hprev + (size_t)dir * NROW * HID;
  for (int k0 = 0; k0 < 256; k0 += 16) {
    As[tx][ty]      = hp[(size_t)(rowBase + ty) * HID + k0 + tx];
    As[tx][ty + 16] = hp[(size_t)(rowBase + ty + 16) * HID + k0 + tx];
#pragma unroll
    for (int rep = 0; rep < 16; ++rep)
      Bs[rep][tid] = rw[(size_t)(k0 + rep) * 1024 + gcol];
    __syncthreads();
    LSTM_INNER(16)
    __syncthreads();
  }

  // ---- fused gate epilogue ----
  const int hcol = h0 + (tx << 2);
  const float4 bI4 = *(const float4*)&bw[hcol];
  const float4 bF4 = *(const float4*)&bw[HID + hcol];
  const float4 bG4 = *(const float4*)&bw[2 * HID + hcol];
  const float4 bO4 = *(const float4*)&bw[3 * HID + hcol];
  const float bIv[4] = {bI4.x, bI4.y, bI4.z, bI4.w};
  const float bFv[4] = {bF4.x, bF4.y, bF4.z, bF4.w};
  const float bGv[4] = {bG4.x, bG4.y, bG4.z, bG4.w};
  const float bOv[4] = {bO4.x, bO4.y, bO4.z, bO4.w};

  auto finish = [&](const float (&accr)[16], int r) {
    const int n = rowBase + (ty << 1) + r;
    float* crow = cst + ((size_t)dir * NROW + n) * HID + hcol;
    const float4 c4 = *(const float4*)crow;
    const float cov[4] = {c4.x, c4.y, c4.z, c4.w};
    float cn[4], hn[4];
#pragma unroll
    for (int s = 0; s < 4; ++s) {
      const float zi = accr[s]      + bIv[s];
      const float zf = accr[4 + s]  + bFv[s];
      const float zg = accr[8 + s]  + bGv[s];
      const float zo = accr[12 + s] + bOv[s];
      const float cc = sigm(zf) * cov[s] + sigm(zi) * tanhf(zg);
      cn[s] = cc;
      hn[s] = sigm(zo) * tanhf(cc);
    }
    *(float4*)crow = make_float4(cn[0], cn[1], cn[2], cn[3]);
    const float4 h4 = make_float4(hn[0], hn[1], hn[2], hn[3]);
    *(float4*)(hnext + ((size_t)dir * NROW + n) * HID + hcol) = h4;
    const int b = n >> 5, sp = n & 31;
    size_t oidx;
    if (VERT)  // hout = v[b][i=seq][j=sp][dir*256+h]
      oidx = (((size_t)(b * 32 + seq)) * 32 + sp) * 512 + (dir << 8) + hcol;
    else       // hout = hfinal[b][i=sp][j=seq][dir*256+h]
      oidx = (((size_t)(b * 32 + sp)) * 32 + seq) * 512 + (dir << 8) + hcol;
    *(float4*)&hout[oidx] = h4;
  };
  finish(acc0, 0);
  finish(acc1, 1);
}

// out[m, c] = relu(hf[m, :512] @ Wd[:, c] + bd[c]) ; 128x128 tile fp32
__global__ __launch_bounds__(256) void dense_relu(
    const float* __restrict__ hf, const float* __restrict__ Wd,
    const float* __restrict__ bd, float* __restrict__ out) {
  const int tid = threadIdx.x;
  const int tx = tid & 15;
  const int ty = tid >> 4;
  const int c0 = blockIdx.x << 7;
  const int m0 = blockIdx.y << 7;

  __shared__ float As[16][132];
  __shared__ float Bs[16][128];

  float acc[8][8];
#pragma unroll
  for (int r = 0; r < 8; ++r)
#pragma unroll
    for (int s = 0; s < 8; ++s) acc[r][s] = 0.f;

  for (int k0 = 0; k0 < 512; k0 += 16) {
    for (int e = tid; e < 2048; e += 256) {
      const int m = e >> 4, kk = e & 15;
      As[kk][m] = hf[(size_t)(m0 + m) * 512 + k0 + kk];
    }
    for (int e = tid; e < 2048; e += 256) {
      const int kk = e >> 7, c = e & 127;
      Bs[kk][c] = Wd[(size_t)(k0 + kk) * 1024 + c0 + c];
    }
    __syncthreads();
#pragma unroll
    for (int kk = 0; kk < 16; ++kk) {
      float a[8], b[8];
#pragma unroll
      for (int r = 0; r < 8; ++r) a[r] = As[kk][(ty << 3) + r];
#pragma unroll
      for (int s = 0; s < 8; ++s) b[s] = Bs[kk][(tx << 3) + s];
#pragma unroll
      for (int r = 0; r < 8; ++r)
#pragma unroll
        for (int s = 0; s < 8; ++s) acc[r][s] += a[r] * b[s];
    }
    __syncthreads();
  }

  const float4 bd0 = *(const float4*)&bd[c0 + (tx << 3)];
  const float4 bd1 = *(const float4*)&bd[c0 + (tx << 3) + 4];
#pragma unroll
  for (int r = 0; r < 8; ++r) {
    const size_t m = (size_t)m0 + (ty << 3) + r;
    float4 o0, o1;
    o0.x = fmaxf(acc[r][0] + bd0.x, 0.f);
    o0.y = fmaxf(acc[r][1] + bd0.y, 0.f);
    o0.z = fmaxf(acc[r][2] + bd0.z, 0.f);
    o0.w = fmaxf(acc[r][3] + bd0.w, 0.f);
    o1.x = fmaxf(acc[r][4] + bd1.x, 0.f);
    o1.y = fmaxf(acc[r][5] + bd1.y, 0.f);
    o1.z = fmaxf(acc[r][6] + bd1.z, 0.f);
    o1.w = fmaxf(acc[r][7] + bd1.w, 0.f);
    *(float4*)&out[m * 1024 + c0 + (tx << 3)] = o0;
    *(float4*)&out[m * 1024 + c0 + (tx << 3) + 4] = o1;
  }
}

}  // namespace

extern "C" void kernel_launch(void* const* d_in, const int* in_sizes, int n_in,
                              void* d_out, int out_size, void* d_ws, size_t ws_size,
                              hipStream_t stream) {
  (void)in_sizes; (void)n_in; (void)out_size; (void)ws_size;
  const float* x    = (const float*)d_in[0];
  const float* k_ud = (const float*)d_in[1];
  const float* r_ud = (const float*)d_in[2];
  const float* b_ud = (const float*)d_in[3];
  const float* k_du = (const float*)d_in[4];
  const float* r_du = (const float*)d_in[5];
  const float* b_du = (const float*)d_in[6];
  const float* k_lr = (const float*)d_in[7];
  const float* r_lr = (const float*)d_in[8];
  const float* b_lr = (const float*)d_in[9];
  const float* k_rl = (const float*)d_in[10];
  const float* r_rl = (const float*)d_in[11];
  const float* b_rl = (const float*)d_in[12];
  const float* Wd   = (const float*)d_in[13];
  const float* bd   = (const float*)d_in[14];
  float* out = (float*)d_out;

  float* ws = (float*)d_ws;
  float* v      = ws;                 // [64][32][32][512]
  float* hfin   = v + VSZ;            // [64][32][32][512]
  float* hping  = hfin + VSZ;         // [2(ping)][2(dir)][2048][256]
  float* cstate = hping + HPSZ;       // [2(dir)][2048][256]

  const dim3 sgrid(4, 64, 2);

  // ---- vertical sweep ----
  hipMemsetAsync(hping, 0, (HPSZ + CSZ) * sizeof(float), stream);
  for (int t = 0; t < 32; ++t) {
    float* hp = hping + (size_t)(t & 1) * (2 * NROW * HID);
    float* hn = hping + (size_t)((t + 1) & 1) * (2 * NROW * HID);
    lstm_step<true><<<sgrid, 256, 0, stream>>>(x, k_ud, r_ud, b_ud, k_du, r_du,
                                               b_du, hp, hn, cstate, v, t);
  }

  // ---- horizontal sweep ----
  hipMemsetAsync(hping, 0, (HPSZ + CSZ) * sizeof(float), stream);
  for (int t = 0; t < 32; ++t) {
    float* hp = hping + (size_t)(t & 1) * (2 * NROW * HID);
    float* hn = hping + (size_t)((t + 1) & 1) * (2 * NROW * HID);
    lstm_step<false><<<sgrid, 256, 0, stream>>>(v, k_lr, r_lr, b_lr, k_rl, r_rl,
                                                b_rl, hp, hn, cstate, hfin, t);
  }

  // ---- dense + relu ----
  dense_relu<<<dim3(8, 512), 256, 0, stream>>>(hfin, Wd, bd, out);
}

// Round 3
// 1602.375 us; speedup vs baseline: 3.9278x; 3.9278x over previous
//
#include <hip/hip_runtime.h>
#include <math.h>
#include <stddef.h>
#include <stdint.h>

// ---------------------------------------------------------------------------
// ReNet: patches -> vert bidir LSTM -> horiz bidir LSTM -> dense+relu
// B=64, I=J=32, D=12, HID=256, FC=1024.
// Round 3: bf16 MFMA everywhere; input projections hoisted out of the
// recurrence; per-step launches (no cooperative launch -- round 2's coop
// launch silently failed, producing all-zero output).
// ---------------------------------------------------------------------------

namespace {

typedef __bf16 bf16x8 __attribute__((ext_vector_type(8)));
typedef float f32x4 __attribute__((ext_vector_type(4)));
typedef __attribute__((address_space(1))) unsigned int as1_uint;
typedef __attribute__((address_space(3))) unsigned int as3_uint;

__device__ __forceinline__ float bf2f(ushort u) {
  return __builtin_bit_cast(float, (unsigned int)u << 16);
}
__device__ __forceinline__ ushort f2bf(float f) {
  unsigned int u = __builtin_bit_cast(unsigned int, f);
  u += 0x7fffu + ((u >> 16) & 1u);
  return (ushort)(u >> 16);
}
__device__ __forceinline__ float sigm(float x) {
  return __fdividef(1.f, 1.f + __expf(-x));
}
__device__ __forceinline__ float tanh_(float x) {
  return 2.f * sigm(2.f * x) - 1.f;
}
__device__ __forceinline__ f32x4 mfma16(bf16x8 a, bf16x8 b, f32x4 c) {
  return __builtin_amdgcn_mfma_f32_16x16x32_bf16(a, b, c, 0, 0, 0);
}
__device__ __forceinline__ void load_lds16(const void* g, void* l) {
  __builtin_amdgcn_global_load_lds((const as1_uint*)g, (as3_uint*)l, 16, 0, 0);
}

// --------------------------------------------------------------------------
// transpose f32 [K][1024] -> bf16 [1024][K]
__global__ __launch_bounds__(256) void transpose_bf16(
    const float* __restrict__ in, ushort* __restrict__ out, int K) {
  const int idx = blockIdx.x * 256 + threadIdx.x;
  if (idx >= (K << 10)) return;
  const int n = idx / K, k = idx - n * K;
  out[idx] = f2bf(in[k * 1024 + n]);
}

// --------------------------------------------------------------------------
// Zv[dir][n=b*32+j][i][1024] = bias + p[(b,i,j)][0:12] @ k[12][1024]
__global__ __launch_bounds__(256) void zxv_kernel(
    const float* __restrict__ x, const float* __restrict__ k0_,
    const float* __restrict__ b0_, const float* __restrict__ k1_,
    const float* __restrict__ b1_, ushort* __restrict__ Z) {
  const int tid = threadIdx.x;
  const int j = blockIdx.x, b = blockIdx.y, dir = blockIdx.z;
  const float* kw_ = dir ? k1_ : k0_;
  const float* bw_ = dir ? b1_ : b0_;
  __shared__ float kw[12][1024];
  __shared__ float ps[32][12];
  for (int e = tid; e < 12 * 1024; e += 256) kw[e >> 10][e & 1023] = kw_[e];
  for (int e = tid; e < 32 * 12; e += 256) {
    const int i = e / 12, q = e - i * 12;
    const int pr = q / 6, rem = q - pr * 6;
    ps[i][q] = x[((size_t)((b * 64 + i * 2 + pr) * 64) + j * 2 + rem / 3) * 3 + rem % 3];
  }
  __syncthreads();
  const int col = tid << 2;
  float4 kr[12];
#pragma unroll
  for (int q = 0; q < 12; ++q) kr[q] = *(const float4*)&kw[q][col];
  const float4 bias4 = *(const float4*)&bw_[col];
  ushort* zb = Z + (((size_t)(dir * 2048 + b * 32 + j)) << 15) + col;
  for (int i = 0; i < 32; ++i) {
    float4 a = bias4;
#pragma unroll
    for (int q = 0; q < 12; ++q) {
      const float p = ps[i][q];
      a.x += p * kr[q].x; a.y += p * kr[q].y;
      a.z += p * kr[q].z; a.w += p * kr[q].w;
    }
    ushort4 o;
    o.x = f2bf(a.x); o.y = f2bf(a.y); o.z = f2bf(a.z); o.w = f2bf(a.w);
    *(ushort4*)(zb + ((size_t)i << 10)) = o;
  }
}

// --------------------------------------------------------------------------
// One bidirectional LSTM step (plain launch). Grid (32 rowblk, 8 hblk, 2 dir),
// 256 threads. Block: rows [rb*64,+64), h-cols [hb*32,+32).
// Z: [2][2048][32][1024] bf16 (bias included).
// hprev/hnext: [2 dir][2048][256] bf16.  cst: [2 dir][2048][256] f32.
// outbuf: [64][32][32][512] bf16 (vert: [b][seq][sp], horiz: [b][sp][seq]).
__global__ __launch_bounds__(256, 2) void lstm_step_mfma(
    const ushort* __restrict__ Z, const ushort* __restrict__ rT,
    const ushort* __restrict__ hprev, ushort* __restrict__ hnext,
    float* __restrict__ cst, ushort* __restrict__ outbuf, int vert, int t) {
  const int tid = threadIdx.x;
  const int lane = tid & 63;
  const int l16 = lane & 15, kg = lane >> 4;
  const int wid = tid >> 6;
  const int wr = wid >> 1, wc = wid & 1;
  const int rb = blockIdx.x, hb = blockIdx.y, dir = (int)blockIdx.z;
  const int rowbase = rb << 6;
  const int seq = dir ? (31 - t) : t;

  __shared__ uint4 rs[128][32];  // [local gate-col][k-chunk], XOR-swizzled

  // stage R tile (128 gate-cols x 256 k), coalesced, swizzle chunk ^= (row&7)
  for (int e = tid; e < 4096; e += 256) {
    const int cc = e >> 5, ch = e & 31;
    const int g = cc >> 5, u = cc & 31;
    const uint4* src =
        (const uint4*)(rT + ((size_t)dir * 1024 + (g << 8) + (hb << 5) + u) * 256);
    rs[cc][ch ^ (cc & 7)] = src[ch];
  }

  const int hcol = (hb << 5) + (wc << 4) + l16;

  // zx prefetch (D-layout rows: kg*4+r)
  float zx[2][4][4];
#pragma unroll
  for (int mt = 0; mt < 2; ++mt) {
#pragma unroll
    for (int r = 0; r < 4; ++r) {
      const int n = rowbase + (wr << 5) + (mt << 4) + (kg << 2) + r;
      const ushort* zp = Z + (((size_t)(dir * 2048 + n) * 32 + seq) << 10) + hcol;
#pragma unroll
      for (int g = 0; g < 4; ++g) zx[mt][g][r] = bf2f(zp[g << 8]);
    }
  }

  // h_prev A-fragments (A-layout rows: l16, k = kk*32 + kg*8)
  uint4 af[2][8];
#pragma unroll
  for (int mt = 0; mt < 2; ++mt) {
    const int n = rowbase + (wr << 5) + (mt << 4) + l16;
#pragma unroll
    for (int kk = 0; kk < 8; ++kk)
      af[mt][kk] =
          *(const uint4*)(hprev + (((size_t)dir * 2048 + n) << 8) + (kk << 5) + (kg << 3));
  }

  __syncthreads();

  f32x4 acc[2][4];
#pragma unroll
  for (int mt = 0; mt < 2; ++mt)
#pragma unroll
    for (int g = 0; g < 4; ++g) acc[mt][g] = (f32x4){0.f, 0.f, 0.f, 0.f};

#pragma unroll
  for (int kk = 0; kk < 8; ++kk) {
    const bf16x8 a0 = __builtin_bit_cast(bf16x8, af[0][kk]);
    const bf16x8 a1 = __builtin_bit_cast(bf16x8, af[1][kk]);
    const int q = (kk << 2) + kg;  // k-chunk index (k = q*8)
#pragma unroll
    for (int g = 0; g < 4; ++g) {
      const int cc = (g << 5) + (wc << 4) + l16;
      const bf16x8 b = __builtin_bit_cast(bf16x8, rs[cc][q ^ (cc & 7)]);
      acc[0][g] = mfma16(a0, b, acc[0][g]);
      acc[1][g] = mfma16(a1, b, acc[1][g]);
    }
  }

  // fused gate epilogue (D rows: kg*4+r, col hcol)
#pragma unroll
  for (int mt = 0; mt < 2; ++mt) {
#pragma unroll
    for (int r = 0; r < 4; ++r) {
      const int n = rowbase + (wr << 5) + (mt << 4) + (kg << 2) + r;
      const float zi = acc[mt][0][r] + zx[mt][0][r];
      const float zf = acc[mt][1][r] + zx[mt][1][r];
      const float zg = acc[mt][2][r] + zx[mt][2][r];
      const float zo = acc[mt][3][r] + zx[mt][3][r];
      float* cp = cst + (((size_t)dir * 2048 + n) << 8) + hcol;
      const float cn = sigm(zf) * (*cp) + sigm(zi) * tanh_(zg);
      *cp = cn;
      const float hv = sigm(zo) * tanh_(cn);
      const ushort h16 = f2bf(hv);
      hnext[(((size_t)dir * 2048 + n) << 8) + hcol] = h16;
      const int b = n >> 5, sp = n & 31;
      const int X = vert ? seq : sp;
      const int Y = vert ? sp : seq;
      outbuf[(((size_t)(b * 32 + X) * 32 + Y) << 9) + (dir << 8) + hcol] = h16;
    }
  }
}

// --------------------------------------------------------------------------
// C[M=65536][1024] = A[M][512] @ BT[1024][512]^T + bias ; EPI 0: bf16 store,
// EPI 1: relu f32 store. 128x128 tile, BK=64, global_load_lds + XOR swizzle.
template <int EPI>
__global__ __launch_bounds__(256) void gemm_bt(
    const ushort* __restrict__ A, const ushort* __restrict__ BT,
    const float* __restrict__ bias, void* __restrict__ Cv) {
  const int tid = threadIdx.x;
  const int lane = tid & 63, wid = tid >> 6;
  const int l16 = lane & 15, kg = lane >> 4;
  const int wr = wid >> 1, wc = wid & 1;
  const int m0 = blockIdx.x << 7, n0 = blockIdx.y << 7;

  __shared__ uint4 As[128][8];
  __shared__ uint4 Bs[128][8];

  f32x4 acc[4][4];
#pragma unroll
  for (int mt = 0; mt < 4; ++mt)
#pragma unroll
    for (int nt = 0; nt < 4; ++nt) acc[mt][nt] = (f32x4){0.f, 0.f, 0.f, 0.f};

  for (int k0 = 0; k0 < 512; k0 += 64) {
#pragma unroll
    for (int c = 0; c < 4; ++c) {
      const int cid = (wid << 8) + (c << 6) + lane;
      const int row = cid >> 3, ch = cid & 7;
      const int sch = ch ^ (row & 7);  // pre-swizzled source (rule 21)
      load_lds16(A + (size_t)(m0 + row) * 512 + k0 + (sch << 3),
                 (uint4*)As + (cid - lane));
      load_lds16(BT + (size_t)(n0 + row) * 512 + k0 + (sch << 3),
                 (uint4*)Bs + (cid - lane));
    }
    __syncthreads();
#pragma unroll
    for (int kk = 0; kk < 2; ++kk) {
      const int q = (kk << 2) + kg;
      bf16x8 a[4], b[4];
#pragma unroll
      for (int mt = 0; mt < 4; ++mt) {
        const int rr = (wr << 6) + (mt << 4) + l16;
        a[mt] = __builtin_bit_cast(bf16x8, As[rr][q ^ (rr & 7)]);
      }
#pragma unroll
      for (int nt = 0; nt < 4; ++nt) {
        const int rr = (wc << 6) + (nt << 4) + l16;
        b[nt] = __builtin_bit_cast(bf16x8, Bs[rr][q ^ (rr & 7)]);
      }
#pragma unroll
      for (int mt = 0; mt < 4; ++mt)
#pragma unroll
        for (int nt = 0; nt < 4; ++nt)
          acc[mt][nt] = mfma16(a[mt], b[nt], acc[mt][nt]);
    }
    __syncthreads();
  }

#pragma unroll
  for (int nt = 0; nt < 4; ++nt) {
    const int n = n0 + (wc << 6) + (nt << 4) + l16;
    const float bn = bias[n];
#pragma unroll
    for (int mt = 0; mt < 4; ++mt) {
#pragma unroll
      for (int r = 0; r < 4; ++r) {
        const size_t m = (size_t)m0 + (wr << 6) + (mt << 4) + (kg << 2) + r;
        const float v = acc[mt][nt][r] + bn;
        if (EPI == 0)
          ((ushort*)Cv)[m * 1024 + n] = f2bf(v);
        else
          ((float*)Cv)[m * 1024 + n] = fmaxf(v, 0.f);
      }
    }
  }
}

}  // namespace

extern "C" void kernel_launch(void* const* d_in, const int* in_sizes, int n_in,
                              void* d_out, int out_size, void* d_ws, size_t ws_size,
                              hipStream_t stream) {
  (void)in_sizes; (void)n_in; (void)out_size; (void)ws_size;
  const float* x    = (const float*)d_in[0];
  const float* k_ud = (const float*)d_in[1];
  const float* r_ud = (const float*)d_in[2];
  const float* b_ud = (const float*)d_in[3];
  const float* k_du = (const float*)d_in[4];
  const float* r_du = (const float*)d_in[5];
  const float* b_du = (const float*)d_in[6];
  const float* k_lr = (const float*)d_in[7];
  const float* r_lr = (const float*)d_in[8];
  const float* b_lr = (const float*)d_in[9];
  const float* k_rl = (const float*)d_in[10];
  const float* r_rl = (const float*)d_in[11];
  const float* b_rl = (const float*)d_in[12];
  const float* Wd   = (const float*)d_in[13];
  const float* bd   = (const float*)d_in[14];

  ushort* W     = (ushort*)d_ws;
  ushort* Z     = W;                      // [2][2048][32][1024]  134217728
  ushort* vbuf  = Z + 134217728;          // [64][32][32][512]     33554432 (also hfin)
  ushort* hping = vbuf + 33554432;        // [2 ping][2 dir][2048][256]  2097152
  ushort* rT    = hping + 2097152;        // [4][1024][256]         1048576
  ushort* kTh   = rT + 1048576;           // [2][1024][512]         1048576
  ushort* WdT   = kTh + 1048576;          // [1024][512]             524288
  float*  cst   = (float*)(WdT + 524288); // [2 dir][2048][256] f32 1048576 f32

  // ---- weight prep (transpose to [N][K] bf16) ----
  transpose_bf16<<<1024, 256, 0, stream>>>(r_ud, rT, 256);
  transpose_bf16<<<1024, 256, 0, stream>>>(r_du, rT + 262144, 256);
  transpose_bf16<<<1024, 256, 0, stream>>>(r_lr, rT + 524288, 256);
  transpose_bf16<<<1024, 256, 0, stream>>>(r_rl, rT + 786432, 256);
  transpose_bf16<<<2048, 256, 0, stream>>>(k_lr, kTh, 512);
  transpose_bf16<<<2048, 256, 0, stream>>>(k_rl, kTh + 524288, 512);
  transpose_bf16<<<2048, 256, 0, stream>>>(Wd, WdT, 512);

  // ---- vertical input projection (K=12) ----
  zxv_kernel<<<dim3(32, 64, 2), 256, 0, stream>>>(x, k_ud, b_ud, k_du, b_du, Z);

  const dim3 sgrid(32, 8, 2);

  // ---- vertical sweep ----
  hipMemsetAsync(hping, 0, 2097152 * sizeof(ushort), stream);
  hipMemsetAsync(cst, 0, 1048576 * sizeof(float), stream);
  for (int t = 0; t < 32; ++t) {
    const ushort* hp = hping + (size_t)(t & 1) * 1048576;
    ushort* hn = hping + (size_t)((t + 1) & 1) * 1048576;
    lstm_step_mfma<<<sgrid, 256, 0, stream>>>(Z, rT, hp, hn, cst, vbuf, 1, t);
  }

  // ---- horizontal input projection: Z = v @ k + b (per dir) ----
  gemm_bt<0><<<dim3(512, 8), 256, 0, stream>>>(vbuf, kTh, b_lr, (void*)Z);
  gemm_bt<0><<<dim3(512, 8), 256, 0, stream>>>(vbuf, kTh + 524288, b_rl,
                                               (void*)(Z + 67108864));

  // ---- horizontal sweep (writes hfin over vbuf; reads only Z) ----
  hipMemsetAsync(hping, 0, 2097152 * sizeof(ushort), stream);
  hipMemsetAsync(cst, 0, 1048576 * sizeof(float), stream);
  for (int t = 0; t < 32; ++t) {
    const ushort* hp = hping + (size_t)(t & 1) * 1048576;
    ushort* hn = hping + (size_t)((t + 1) & 1) * 1048576;
    lstm_step_mfma<<<sgrid, 256, 0, stream>>>(Z, rT + 524288, hp, hn, cst, vbuf,
                                              0, t);
  }

  // ---- dense + relu ----
  gemm_bt<1><<<dim3(512, 8), 256, 0, stream>>>(vbuf, WdT, bd, d_out);
}